// Round 2
// baseline (210.124 us; speedup 1.0000x reference)
//
#include <hip/hip_runtime.h>
#include <hip/hip_fp16.h>

// ---------------------------------------------------------------------------
// EmbeddingClassifier: out[32768,1000] = -arccosh(poincare_arg) * scale
//   x  = expmap0(fea @ W^T + b)      [32768,256]
//   p  = expmap0(emb)                [1000,256]
//   out[i,c] = -arccosh(max(1 + 2*max(xs+ps-2*x.p,0)/max((1-xs)(1-ps),EPS), 1+EPS))
// Strategy: fp16 MFMA (16x16x32) for both GEMMs, fp32 row stats, fused kernel.
// Fallback: if ws_size < WS_BYTES, run a ws-free fp32 kernel (correct, slower).
// ---------------------------------------------------------------------------

#define EPSF 1e-5f

typedef _Float16 half8 __attribute__((ext_vector_type(8)));
typedef _Float16 half4v __attribute__((ext_vector_type(4)));
typedef float f32x4 __attribute__((ext_vector_type(4)));

typedef __attribute__((address_space(3))) unsigned int as3_u32;
typedef __attribute__((address_space(1))) unsigned int as1_u32;
#define GLOAD16(gp, lp) __builtin_amdgcn_global_load_lds(  \
    (const as1_u32*)(gp), (as3_u32*)(lp), 16, 0, 0)

static __device__ __forceinline__ f32x4 mfma16(half8 a, half8 b, f32x4 c) {
  return __builtin_amdgcn_mfma_f32_16x16x32_f16(a, b, c, 0, 0, 0);
}

// ws layout (all images are LDS-ready: swizzled byte ^= ((row&7)<<4) inside 512/256B rows)
#define PROTO_OFF 0                      // 1024 rows * 512 B  (fp16, swizzled)
#define PSQ_OFF   (1024 * 512)           // 1024 f32
#define WIMG_OFF  (1024 * 512 + 4096)    // 2 chunks * 256 rows * 256 B (fp16, swizzled)
#define WS_BYTES  (WIMG_OFF + 2 * 65536)

#define LDS_SZ (65536 + 65536 + 512 + 1024)

// ---------------------------------------------------------------------------
// Prep: build expmap'd proto image + p_sq, and fp16 W image (k-chunked).
// blocks 0..255: protos (4 rows/block, one per wave). blocks 256..319: W.
// ---------------------------------------------------------------------------
__global__ __launch_bounds__(256) void prep_kernel(const float* __restrict__ W,
                                                   const float* __restrict__ emb,
                                                   char* __restrict__ ws) {
  const int blk = blockIdx.x;
  const int tid = threadIdx.x;
  if (blk < 256) {
    const int wave = tid >> 6, lane = tid & 63;
    const int row = blk * 4 + wave;          // 0..1023 (1000 real + 24 pad)
    float4 v = {0.f, 0.f, 0.f, 0.f};
    if (row < 1000) v = ((const float4*)emb)[row * 64 + lane];
    float s = v.x * v.x + v.y * v.y + v.z * v.z + v.w * v.w;
#pragma unroll
    for (int m = 1; m < 64; m <<= 1) s += __shfl_xor(s, m, 64);
    float r  = sqrtf(s);
    float rc = fmaxf(r, EPSF);
    float e  = __expf(2.0f * rc);
    float t  = 1.0f - 2.0f / (e + 1.0f);     // tanh(rc)
    float sc = t / rc;
    float ps = t * t;                        // == sum(p*p) analytically
    if (row >= 1000) { sc = 0.0f; ps = 0.0f; }
    half4v h;
    h[0] = (_Float16)(v.x * sc); h[1] = (_Float16)(v.y * sc);
    h[2] = (_Float16)(v.z * sc); h[3] = (_Float16)(v.w * sc);
    const int byte = (lane * 8) ^ ((row & 7) << 4);   // swizzled position
    *(half4v*)(ws + PROTO_OFF + row * 512 + byte) = h;
    if (lane == 0) ((float*)(ws + PSQ_OFF))[row] = ps;
  } else {
    // W image: x[i,j] = sum_k fea[i,k]*W[j,k] -> B operand rows are W rows.
    const int e4 = (blk - 256) * 256 + tid;  // float4 index, 0..16383
    const int n  = e4 >> 6;                  // 0..255 output col (B row)
    const int k4 = e4 & 63;
    const int k  = k4 * 4;
    float4 v = ((const float4*)W)[n * 64 + k4];
    const int c  = k >> 7;                   // k-chunk (128 each)
    const int kl = k & 127;
    half4v h;
    h[0] = (_Float16)v.x; h[1] = (_Float16)v.y;
    h[2] = (_Float16)v.z; h[3] = (_Float16)v.w;
    const int byte = (kl * 2) ^ ((n & 7) << 4);
    *(half4v*)(ws + WIMG_OFF + c * 65536 + n * 256 + byte) = h;
  }
}

// ---------------------------------------------------------------------------
// Main fused kernel: 256 blocks (1/CU) x 256 threads (4 waves). BM=128 rows.
// ---------------------------------------------------------------------------
__global__ __launch_bounds__(256, 1) void main_kernel(
    const float* __restrict__ fea, const float* __restrict__ bvec,
    const float* __restrict__ lsc, const char* __restrict__ ws,
    float* __restrict__ out) {
  extern __shared__ char lds[];
  char* regA = lds;                    // 64 KiB: fea_f16, later proto tiles
  char* regB = lds + 65536;            // 64 KiB: W chunks, later x_f16
  float* xsq = (float*)(lds + 131072); // 128 f32
  float* bl  = (float*)(lds + 131072 + 512); // 256 f32

  const int tid  = threadIdx.x;
  const int wave = tid >> 6, lane = tid & 63;
  const int g = lane >> 4, i = lane & 15;
  const int m0 = blockIdx.x * 128;
  const int xr = (i & 7) << 4;         // per-lane LDS swizzle key

  const char*  wimg  = ws + WIMG_OFF;
  const char*  pimg  = ws + PROTO_OFF;
  const float* psq_g = (const float*)(ws + PSQ_OFF);

  // ---- stage W chunk 0 (async DMA) + b + features(f32->f16, swizzled) ----
  for (int j = wave; j < 64; j += 4) GLOAD16(wimg + j * 1024 + lane * 16, regB + j * 1024);
  bl[tid] = bvec[tid];
#pragma unroll
  for (int j = 0; j < 16; ++j) {
    const int u = j * 256 + tid;
    const int row = u >> 5, c8 = u & 31;     // 32 x 16B blocks per 512B row
    const float4* p = (const float4*)fea + (size_t)(m0 + row) * 64 + c8 * 2;
    float4 a = p[0], b4 = p[1];
    half8 h = {(_Float16)a.x,  (_Float16)a.y,  (_Float16)a.z,  (_Float16)a.w,
               (_Float16)b4.x, (_Float16)b4.y, (_Float16)b4.z, (_Float16)b4.w};
    *(half8*)(regA + row * 512 + ((c8 * 16) ^ ((row & 7) << 4))) = h;
  }
  __syncthreads();

  // ---- phase 1: x_lin = fea @ W^T.  wave owns rows [wave*32, wave*32+32) ----
  f32x4 accP[2][16];
  const f32x4 zero4 = {0.f, 0.f, 0.f, 0.f};
#pragma unroll
  for (int rf = 0; rf < 2; ++rf)
#pragma unroll
    for (int cf = 0; cf < 16; ++cf) accP[rf][cf] = zero4;

#pragma unroll
  for (int c = 0; c < 2; ++c) {
    if (c == 1) {
      __syncthreads();   // everyone done reading chunk 0
      for (int j = wave; j < 64; j += 4) GLOAD16(wimg + 65536 + j * 1024 + lane * 16, regB + j * 1024);
      __syncthreads();   // chunk 1 resident
    }
#pragma unroll
    for (int ks = 0; ks < 4; ++ks) {
      const int kb  = ks * 64 + g * 16;            // byte off in 256B W row
      const int kbA = c * 256 + kb;                // byte off in 512B fea row
      half8 a0 = *(half8*)(regA + (wave * 32 + 0 + i) * 512 + (kbA ^ xr));
      half8 a1 = *(half8*)(regA + (wave * 32 + 16 + i) * 512 + (kbA ^ xr));
#pragma unroll
      for (int cf = 0; cf < 16; ++cf) {
        half8 b8 = *(half8*)(regB + (cf * 16 + i) * 256 + (kb ^ xr));
        accP[0][cf] = mfma16(a0, b8, accP[0][cf]);
        accP[1][cf] = mfma16(a1, b8, accP[1][cf]);
      }
    }
  }

  // ---- bias + row sq-sums (C/D layout: col=i, row=g*4+reg) ----
  float ssum[2][4] = {{0.f,0.f,0.f,0.f},{0.f,0.f,0.f,0.f}};
#pragma unroll
  for (int rf = 0; rf < 2; ++rf)
#pragma unroll
    for (int cf = 0; cf < 16; ++cf) {
      const float bc = bl[i + 16 * cf];
#pragma unroll
      for (int reg = 0; reg < 4; ++reg) {
        accP[rf][cf][reg] += bc;
        ssum[rf][reg] = fmaf(accP[rf][cf][reg], accP[rf][cf][reg], ssum[rf][reg]);
      }
    }
#pragma unroll
  for (int m = 1; m < 16; m <<= 1)
#pragma unroll
    for (int rf = 0; rf < 2; ++rf)
#pragma unroll
      for (int reg = 0; reg < 4; ++reg) ssum[rf][reg] += __shfl_xor(ssum[rf][reg], m, 64);

  float scl[2][4], xsv[2][4];
#pragma unroll
  for (int rf = 0; rf < 2; ++rf)
#pragma unroll
    for (int reg = 0; reg < 4; ++reg) {
      float r  = sqrtf(ssum[rf][reg]);
      float rc = fmaxf(r, EPSF);
      float e  = __expf(2.0f * rc);
      float t  = 1.0f - 2.0f / (e + 1.0f);
      scl[rf][reg] = t / rc;
      xsv[rf][reg] = t * t;              // x_sq in fp32 (critical for denom clamp)
    }
  __syncthreads();   // all waves finished reading W chunk 1 / fea

  // ---- write x (f16, swizzled) into regB; x_sq to LDS; prefetch proto 0 ----
#pragma unroll
  for (int rf = 0; rf < 2; ++rf)
#pragma unroll
    for (int cf = 0; cf < 16; ++cf)
#pragma unroll
      for (int reg = 0; reg < 4; ++reg) {
        const int row = wave * 32 + rf * 16 + g * 4 + reg;
        const int col = i + 16 * cf;
        *(_Float16*)(regB + row * 512 + ((col * 2) ^ ((row & 7) << 4))) =
            (_Float16)(accP[rf][cf][reg] * scl[rf][reg]);
      }
  if (i < 8) {
    const int rf = i >> 2, reg = i & 3;
    xsq[wave * 32 + rf * 16 + g * 4 + reg] = xsv[rf][reg];
  }
  for (int j = wave; j < 64; j += 4) GLOAD16(pimg + j * 1024 + lane * 16, regA + j * 1024);
  __syncthreads();   // x visible + proto tile 0 resident

  // ---- phase 2: 8 proto tiles of 128 cols. wave tile 64x64 (2x2 grid) ----
  const int wr = (wave >> 1) * 64, wc = (wave & 1) * 64;
  const float sc_out = fminf(__expf(lsc[0]), 100.0f);
  float xs_l[4][4];
#pragma unroll
  for (int rf = 0; rf < 4; ++rf)
#pragma unroll
    for (int reg = 0; reg < 4; ++reg) xs_l[rf][reg] = xsq[wr + rf * 16 + g * 4 + reg];

  for (int nt = 0; nt < 8; ++nt) {
    f32x4 acc[4][4];
#pragma unroll
    for (int rf = 0; rf < 4; ++rf)
#pragma unroll
      for (int cf = 0; cf < 4; ++cf) acc[rf][cf] = zero4;

#pragma unroll
    for (int ks = 0; ks < 8; ++ks) {
      const int kb = ks * 64 + g * 16;
      half8 A[4], B[4];
#pragma unroll
      for (int rf = 0; rf < 4; ++rf) A[rf] = *(half8*)(regB + (wr + rf * 16 + i) * 512 + (kb ^ xr));
#pragma unroll
      for (int cf = 0; cf < 4; ++cf) B[cf] = *(half8*)(regA + (wc + cf * 16 + i) * 512 + (kb ^ xr));
#pragma unroll
      for (int rf = 0; rf < 4; ++rf)
#pragma unroll
        for (int cf = 0; cf < 4; ++cf) acc[rf][cf] = mfma16(A[rf], B[cf], acc[rf][cf]);
    }
    __syncthreads();   // done reading proto tile nt
    if (nt < 7)        // async prefetch next tile; overlaps epilogue below
      for (int j = wave; j < 64; j += 4)
        GLOAD16(pimg + (size_t)(nt + 1) * 65536 + j * 1024 + lane * 16, regA + j * 1024);

    // epilogue: poincare distance + store
#pragma unroll
    for (int cf = 0; cf < 4; ++cf) {
      const int col = nt * 128 + wc + cf * 16 + i;
      const bool ok = col < 1000;
      const float ps  = ok ? psq_g[col] : 0.0f;
      const float omp = 1.0f - ps;
#pragma unroll
      for (int rf = 0; rf < 4; ++rf)
#pragma unroll
        for (int reg = 0; reg < 4; ++reg) {
          const float xs   = xs_l[rf][reg];
          const float dot  = acc[rf][cf][reg];
          const float diff = fmaxf(fmaf(-2.0f, dot, xs + ps), 0.0f);
          const float den  = fmaxf((1.0f - xs) * omp, EPSF);
          const float arg  = fmaxf(fmaf(2.0f * diff, __builtin_amdgcn_rcpf(den), 1.0f),
                                   1.0f + EPSF);
          const float sq   = __builtin_amdgcn_sqrtf(fmaf(arg, arg, -1.0f));
          const float dist = __logf(arg + sq);
          if (ok)
            out[(size_t)(m0 + wr + rf * 16 + g * 4 + reg) * 1000 + col] = -dist * sc_out;
        }
    }
    if (nt < 7) __syncthreads();   // prefetch drained (vmcnt via barrier)
  }
}

// ---------------------------------------------------------------------------
// Fallback (ws-free, all fp32): only used if ws_size < WS_BYTES. Correctness
// insurance against an undersized harness workspace; ~10x slower, never used
// if the workspace is adequate.
// ---------------------------------------------------------------------------
__global__ __launch_bounds__(256) void fallback_kernel(
    const float* __restrict__ fea, const float* __restrict__ W,
    const float* __restrict__ b, const float* __restrict__ emb,
    const float* __restrict__ lsc, float* __restrict__ out) {
  __shared__ float fr_[16][256];
  __shared__ float xr_[16][256];
  __shared__ float xs_[16];
  const int tid  = threadIdx.x;
  const int row0 = blockIdx.x * 16;

  for (int u = tid; u < 16 * 256; u += 256)
    fr_[u >> 8][u & 255] = fea[(size_t)(row0 + (u >> 8)) * 256 + (u & 255)];
  __syncthreads();

  // thread j computes x_lin[r][j] for all 16 rows
  float acc[16];
  const float bj = b[tid];
#pragma unroll
  for (int r = 0; r < 16; ++r) acc[r] = bj;
  for (int k = 0; k < 256; ++k) {
    const float w = W[(size_t)tid * 256 + k];
#pragma unroll
    for (int r = 0; r < 16; ++r) acc[r] = fmaf(fr_[r][k], w, acc[r]);
  }
#pragma unroll
  for (int r = 0; r < 16; ++r) xr_[r][tid] = acc[r];
  __syncthreads();

  if (tid < 16) {
    float s = 0.f;
    for (int k = 0; k < 256; ++k) s = fmaf(xr_[tid][k], xr_[tid][k], s);
    const float rn = sqrtf(s), rc = fmaxf(rn, EPSF);
    const float e = __expf(2.f * rc), t = 1.f - 2.f / (e + 1.f);
    xs_[tid] = t * t;
    fr_[tid][0] = t / rc;              // reuse fr_ as scale scratch
  }
  __syncthreads();
  for (int u = tid; u < 16 * 256; u += 256)
    xr_[u >> 8][u & 255] *= fr_[u >> 8][0];
  __syncthreads();

  const float sc_out = fminf(__expf(lsc[0]), 100.0f);
  for (int c = tid; c < 1000; c += 256) {
    float s = 0.f;
    for (int k = 0; k < 256; ++k) {
      const float e0 = emb[(size_t)c * 256 + k];
      s = fmaf(e0, e0, s);
    }
    const float rn = sqrtf(s), rc = fmaxf(rn, EPSF);
    const float e = __expf(2.f * rc), t = 1.f - 2.f / (e + 1.f);
    const float psc = t / rc, ps = t * t, omp = 1.f - ps;
    float dots[16];
#pragma unroll
    for (int r = 0; r < 16; ++r) dots[r] = 0.f;
    for (int k = 0; k < 256; ++k) {
      const float pk = emb[(size_t)c * 256 + k] * psc;
#pragma unroll
      for (int r = 0; r < 16; ++r) dots[r] = fmaf(xr_[r][k], pk, dots[r]);
    }
#pragma unroll
    for (int r = 0; r < 16; ++r) {
      const float xs = xs_[r];
      const float diff = fmaxf(xs + ps - 2.f * dots[r], 0.f);
      const float den  = fmaxf((1.f - xs) * omp, EPSF);
      const float arg  = fmaxf(1.f + 2.f * diff / den, 1.f + EPSF);
      const float d    = logf(arg + sqrtf(fmaf(arg, arg, -1.f)));
      out[(size_t)(row0 + r) * 1000 + c] = -d * sc_out;
    }
  }
}

// ---------------------------------------------------------------------------
extern "C" void kernel_launch(void* const* d_in, const int* in_sizes, int n_in,
                              void* d_out, int out_size, void* d_ws, size_t ws_size,
                              hipStream_t stream) {
  (void)in_sizes; (void)n_in; (void)out_size;
  const float* fea = (const float*)d_in[0];
  const float* W   = (const float*)d_in[1];
  const float* b   = (const float*)d_in[2];
  const float* emb = (const float*)d_in[3];
  const float* ls  = (const float*)d_in[4];
  float* out = (float*)d_out;
  char*  ws  = (char*)d_ws;

  if (ws_size >= (size_t)WS_BYTES) {
    hipFuncSetAttribute((const void*)main_kernel,
                        hipFuncAttributeMaxDynamicSharedMemorySize, LDS_SZ);
    prep_kernel<<<320, 256, 0, stream>>>(W, emb, ws);
    main_kernel<<<256, 256, LDS_SZ, stream>>>(fea, b, ls, ws, out);
  } else {
    fallback_kernel<<<2048, 256, 0, stream>>>(fea, W, b, emb, ls, out);
  }
}

// Round 4
// 190.209 us; speedup vs baseline: 1.1047x; 1.1047x over previous
//
#include <hip/hip_runtime.h>
#include <hip/hip_fp16.h>

// ---------------------------------------------------------------------------
// EmbeddingClassifier: out[32768,1000] = -arccosh(poincare_arg) * scale
//   x  = expmap0(fea @ W^T + b)      [32768,256]
//   p  = expmap0(emb)                [1000,256]
// v3b: fused main kernel. 512 blocks x 256 thr (4 waves), 64 KB static LDS
// -> 2 blocks/CU (8 waves/CU). W self-staged per block (dbuf); x kept in
// registers (A-frags) after an LDS wave-local transpose; proto tiles
// double-buffered via global_load_lds with counted vmcnt waits so output
// stores are never drained at barriers. psq loads issued before stage DMAs
// so the compiler's implicit wait doesn't drain the stage; sched_barrier(0)
// after raw barriers (hoist insurance); ln2 folded into output scale.
// ws usage: 516 KB proto image + psq (proven safe in round 2).
// ---------------------------------------------------------------------------

#define EPSF 1e-5f

typedef _Float16 half8 __attribute__((ext_vector_type(8)));
typedef _Float16 half4v __attribute__((ext_vector_type(4)));
typedef float f32x4 __attribute__((ext_vector_type(4)));

typedef __attribute__((address_space(3))) unsigned int as3_u32;
typedef __attribute__((address_space(1))) unsigned int as1_u32;
#define GLOAD16(gp, lp) __builtin_amdgcn_global_load_lds(  \
    (const as1_u32*)(gp), (as3_u32*)(lp), 16, 0, 0)

static __device__ __forceinline__ f32x4 mfma16(half8 a, half8 b, f32x4 c) {
  return __builtin_amdgcn_mfma_f32_16x16x32_f16(a, b, c, 0, 0, 0);
}

// ws layout: proto image (1024 rows x 512B, fp16, swizzled byte^=((row&7)<<4))
// + p_sq. Total 516 KB.
#define PROTO_OFF 0
#define PSQ_OFF   (1024 * 512)
#define WS_BYTES  (PSQ_OFF + 4096)

// ---------------------------------------------------------------------------
// Prep: expmap'd proto image + p_sq (pad rows 1000..1023 with zeros).
// ---------------------------------------------------------------------------
__global__ __launch_bounds__(256) void prep_kernel(const float* __restrict__ emb,
                                                   char* __restrict__ ws) {
  const int tid = threadIdx.x;
  const int wave = tid >> 6, lane = tid & 63;
  const int row = blockIdx.x * 4 + wave;     // 0..1023
  float4 v = {0.f, 0.f, 0.f, 0.f};
  if (row < 1000) v = ((const float4*)emb)[row * 64 + lane];
  float s = v.x * v.x + v.y * v.y + v.z * v.z + v.w * v.w;
#pragma unroll
  for (int m = 1; m < 64; m <<= 1) s += __shfl_xor(s, m, 64);
  float r  = sqrtf(s);
  float rc = fmaxf(r, EPSF);
  float e  = __expf(2.0f * rc);
  float t  = 1.0f - 2.0f / (e + 1.0f);       // tanh(rc)
  float sc = t / rc;
  float ps = t * t;                          // == |p|^2 analytically
  if (row >= 1000) { sc = 0.0f; ps = 0.0f; }
  half4v h;
  h[0] = (_Float16)(v.x * sc); h[1] = (_Float16)(v.y * sc);
  h[2] = (_Float16)(v.z * sc); h[3] = (_Float16)(v.w * sc);
  const int byte = (lane * 8) ^ ((row & 7) << 4);
  *(half4v*)(ws + PROTO_OFF + row * 512 + byte) = h;
  if (lane == 0) ((float*)(ws + PSQ_OFF))[row] = ps;
}

// ---------------------------------------------------------------------------
// Fused main kernel: grid 512 x 256 threads, 64 rows/block, 64 KB LDS.
// ---------------------------------------------------------------------------
__global__ __launch_bounds__(256, 2) void fused_kernel(
    const float* __restrict__ fea, const float* __restrict__ W,
    const float* __restrict__ bvec, const float* __restrict__ lsc,
    const char* __restrict__ ws, float* __restrict__ out) {
  __shared__ char lds[65536];
  char* buf0 = lds;
  char* buf1 = lds + 32768;

  const int tid  = threadIdx.x;
  const int w    = tid >> 6, lane = tid & 63;
  const int g = lane >> 4, i = lane & 15;
  const int xr = (i & 7) << 4;
  const int m0 = blockIdx.x * 64;

  const char*  pimg  = ws + PROTO_OFF;
  const float* psq_g = (const float*)(ws + PSQ_OFF);

  // ================= Phase 1: x_lin = fea @ W^T (K chunks of 64) ============
  const f32x4 z4 = {0.f, 0.f, 0.f, 0.f};
  f32x4 accW[16];
#pragma unroll
  for (int cf = 0; cf < 16; ++cf) accW[cf] = z4;

  // stage W K-chunk c (f32 -> f16, swizzled) into dst (32 KB: 256 n x 128 B)
  auto stageW = [&](int c, char* dst) {
#pragma unroll
    for (int p = 0; p < 8; ++p) {
      const int u = p * 256 + tid;           // 2048 granules of 8 floats
      const int n = u >> 3, k8 = u & 7;
      const float4* src = (const float4*)(W + (size_t)n * 256 + c * 64 + k8 * 8);
      float4 v0 = src[0], v1 = src[1];
      half8 h = {(_Float16)v0.x, (_Float16)v0.y, (_Float16)v0.z, (_Float16)v0.w,
                 (_Float16)v1.x, (_Float16)v1.y, (_Float16)v1.z, (_Float16)v1.w};
      *(half8*)(dst + n * 128 + ((k8 * 16) ^ ((n & 7) << 4))) = h;
    }
  };
  // MFMA over chunk c: A from fea (f32->f16 in reg), B from LDS chunk
  auto mfmaW = [&](int c, const char* bsrc) {
#pragma unroll
    for (int ksl = 0; ksl < 2; ++ksl) {      // K=32 slices within the 64-chunk
      const float4* ap = (const float4*)(fea +
          (size_t)(m0 + w * 16 + i) * 256 + c * 64 + ksl * 32 + g * 8);
      float4 a0 = ap[0], a1 = ap[1];
      half8 a = {(_Float16)a0.x, (_Float16)a0.y, (_Float16)a0.z, (_Float16)a0.w,
                 (_Float16)a1.x, (_Float16)a1.y, (_Float16)a1.z, (_Float16)a1.w};
#pragma unroll
      for (int cf = 0; cf < 16; ++cf) {
        half8 b = *(const half8*)(bsrc + (cf * 16 + i) * 128 +
                                  ((ksl * 64 + g * 16) ^ xr));
        accW[cf] = mfma16(a, b, accW[cf]);
      }
    }
  };

  stageW(0, buf0); __syncthreads();
  stageW(1, buf1); mfmaW(0, buf0); __syncthreads();
  stageW(2, buf0); mfmaW(1, buf1); __syncthreads();
  stageW(3, buf1); mfmaW(2, buf0); __syncthreads();
  mfmaW(3, buf1);  __syncthreads();

  // ======= proto tile 0 staging issued EARLY (overlaps epilogue1) ==========
  auto stageP = [&](int nt, char* dst) {
#pragma unroll
    for (int p = 0; p < 8; ++p) {
      const int chunk = p * 4 + w;           // 32 KB tile = 32 x 1 KB chunks
      GLOAD16(pimg + (size_t)nt * 32768 + chunk * 1024 + lane * 16,
              dst + chunk * 1024);
    }
  };
  stageP(0, buf1);

  // ================= epilogue 1: bias + row norms + expmap ==================
  float ssum[4] = {0.f, 0.f, 0.f, 0.f};
#pragma unroll
  for (int cf = 0; cf < 16; ++cf) {
    const float bc = bvec[cf * 16 + i];
#pragma unroll
    for (int r = 0; r < 4; ++r) {
      accW[cf][r] += bc;
      ssum[r] = fmaf(accW[cf][r], accW[cf][r], ssum[r]);
    }
  }
#pragma unroll
  for (int m = 1; m < 16; m <<= 1)
#pragma unroll
    for (int r = 0; r < 4; ++r) ssum[r] += __shfl_xor(ssum[r], m, 64);

  float scl[4], xsv[4];
#pragma unroll
  for (int r = 0; r < 4; ++r) {
    float rn = sqrtf(ssum[r]);
    float rc = fmaxf(rn, EPSF);
    float e  = __expf(2.0f * rc);
    float t  = 1.0f - 2.0f / (e + 1.0f);
    scl[r] = t / rc;
    xsv[r] = t * t;                          // x_sq in f32 (exact denom clamp)
  }

  // ====== x transpose through wave-private LDS slice -> A-frags in regs =====
  char* xsl = buf0 + w * 8192;               // 16 rows x 512 B per wave
#pragma unroll
  for (int cf = 0; cf < 16; ++cf)
#pragma unroll
    for (int r = 0; r < 4; ++r) {
      const int row = g * 4 + r;
      *(_Float16*)(xsl + row * 512 + (((cf * 16 + i) * 2) ^ ((row & 7) << 4))) =
          (_Float16)(accW[cf][r] * scl[r]);
    }
  half8 A[8];
#pragma unroll
  for (int ks = 0; ks < 8; ++ks)
    A[ks] = *(const half8*)(xsl + i * 512 + ((ks * 64 + g * 16) ^ xr));

  // -scale*ln(z) = -(scale*ln2)*log2(z)
  const float sc_ln2 = fminf(__expf(lsc[0]), 100.0f) * 0.69314718055994531f;

  // tile 0 resident + all x reads landed before buf0 gets overwritten
  asm volatile("s_waitcnt vmcnt(0) lgkmcnt(0)" ::: "memory");
  __builtin_amdgcn_s_barrier();
  __builtin_amdgcn_sched_barrier(0);

  // ================= Phase 2: 16 proto tiles of 64 cols =====================
  auto stepP = [&](int nt, const char* cur, char* nxt) {
    // psq loads FIRST: the compiler's wait before their use then only needs
    // vmcnt(8) (leaves the 8 stage DMAs below in flight through the epilogue)
    float psq[4];
#pragma unroll
    for (int cf = 0; cf < 4; ++cf) psq[cf] = psq_g[nt * 64 + cf * 16 + i];

    if (nt < 15) stageP(nt + 1, nxt);        // DMAs issued BEFORE stores

    f32x4 acc[4] = {z4, z4, z4, z4};
#pragma unroll
    for (int ks = 0; ks < 8; ++ks) {
#pragma unroll
      for (int cf = 0; cf < 4; ++cf) {
        half8 b = *(const half8*)(cur + (cf * 16 + i) * 512 +
                                  ((ks * 64 + g * 16) ^ xr));
        acc[cf] = mfma16(A[ks], b, acc[cf]);
      }
    }
#pragma unroll
    for (int cf = 0; cf < 4; ++cf) {
      const float ps = psq[cf], omp = 1.0f - ps;
      const int col = nt * 64 + cf * 16 + i;
#pragma unroll
      for (int r = 0; r < 4; ++r) {
        const float xs   = xsv[r];
        const float diff = fmaxf(fmaf(-2.0f, acc[cf][r], xs + ps), 0.0f);
        const float den  = fmaxf((1.0f - xs) * omp, EPSF);
        const float arg  = fmaxf(fmaf(2.0f * diff, __builtin_amdgcn_rcpf(den), 1.0f),
                                 1.0f + EPSF);
        const float sq   = __builtin_amdgcn_sqrtf(fmaf(arg, arg, -1.0f));
        const float dist = __log2f(arg + sq);
        if (col < 1000)
          out[(size_t)(m0 + w * 16 + g * 4 + r) * 1000 + col] = -dist * sc_ln2;
      }
    }
    if (nt < 15) {
      // counted wait: retires the 8 stage DMAs (oldest outstanding) while
      // leaving the 16 stores in flight across the barrier
      asm volatile("s_waitcnt vmcnt(16)" ::: "memory");
      __builtin_amdgcn_s_barrier();
      __builtin_amdgcn_sched_barrier(0);
    }
  };

  for (int nt2 = 0; nt2 < 16; nt2 += 2) {
    stepP(nt2,     buf1, buf0);
    stepP(nt2 + 1, buf0, buf1);
  }
}

// ---------------------------------------------------------------------------
// Fallback (ws-free, fp32) — only if ws_size < WS_BYTES. Insurance.
// ---------------------------------------------------------------------------
__global__ __launch_bounds__(256) void fallback_kernel(
    const float* __restrict__ fea, const float* __restrict__ W,
    const float* __restrict__ b, const float* __restrict__ emb,
    const float* __restrict__ lsc, float* __restrict__ out) {
  __shared__ float fr_[16][256];
  __shared__ float xr_[16][256];
  __shared__ float xs_[16];
  const int tid  = threadIdx.x;
  const int row0 = blockIdx.x * 16;

  for (int u = tid; u < 16 * 256; u += 256)
    fr_[u >> 8][u & 255] = fea[(size_t)(row0 + (u >> 8)) * 256 + (u & 255)];
  __syncthreads();

  float acc[16];
  const float bj = b[tid];
#pragma unroll
  for (int r = 0; r < 16; ++r) acc[r] = bj;
  for (int k = 0; k < 256; ++k) {
    const float wv = W[(size_t)tid * 256 + k];
#pragma unroll
    for (int r = 0; r < 16; ++r) acc[r] = fmaf(fr_[r][k], wv, acc[r]);
  }
#pragma unroll
  for (int r = 0; r < 16; ++r) xr_[r][tid] = acc[r];
  __syncthreads();

  if (tid < 16) {
    float s = 0.f;
    for (int k = 0; k < 256; ++k) s = fmaf(xr_[tid][k], xr_[tid][k], s);
    const float rn = sqrtf(s), rc = fmaxf(rn, EPSF);
    const float e = __expf(2.f * rc), t = 1.f - 2.f / (e + 1.f);
    xs_[tid] = t * t;
    fr_[tid][0] = t / rc;
  }
  __syncthreads();
  for (int u = tid; u < 16 * 256; u += 256)
    xr_[u >> 8][u & 255] *= fr_[u >> 8][0];
  __syncthreads();

  const float sc_out = fminf(__expf(lsc[0]), 100.0f);
  for (int c = tid; c < 1000; c += 256) {
    float s = 0.f;
    for (int k = 0; k < 256; ++k) {
      const float e0 = emb[(size_t)c * 256 + k];
      s = fmaf(e0, e0, s);
    }
    const float rn = sqrtf(s), rc = fmaxf(rn, EPSF);
    const float e = __expf(2.f * rc), t = 1.f - 2.f / (e + 1.f);
    const float psc = t / rc, ps = t * t, omp = 1.f - ps;
    float dots[16];
#pragma unroll
    for (int r = 0; r < 16; ++r) dots[r] = 0.f;
    for (int k = 0; k < 256; ++k) {
      const float pk = emb[(size_t)c * 256 + k] * psc;
#pragma unroll
      for (int r = 0; r < 16; ++r) dots[r] = fmaf(xr_[r][k], pk, dots[r]);
    }
#pragma unroll
    for (int r = 0; r < 16; ++r) {
      const float xs = xs_[r];
      const float diff = fmaxf(xs + ps - 2.f * dots[r], 0.f);
      const float den  = fmaxf((1.f - xs) * omp, EPSF);
      const float arg  = fmaxf(1.f + 2.f * diff / den, 1.f + EPSF);
      const float d    = logf(arg + sqrtf(fmaf(arg, arg, -1.f)));
      out[(size_t)(row0 + r) * 1000 + c] = -d * sc_out;
    }
  }
}

// ---------------------------------------------------------------------------
extern "C" void kernel_launch(void* const* d_in, const int* in_sizes, int n_in,
                              void* d_out, int out_size, void* d_ws, size_t ws_size,
                              hipStream_t stream) {
  (void)in_sizes; (void)n_in; (void)out_size;
  const float* fea = (const float*)d_in[0];
  const float* W   = (const float*)d_in[1];
  const float* b   = (const float*)d_in[2];
  const float* emb = (const float*)d_in[3];
  const float* ls  = (const float*)d_in[4];
  float* out = (float*)d_out;
  char*  ws  = (char*)d_ws;

  if (ws_size >= (size_t)WS_BYTES) {
    prep_kernel<<<256, 256, 0, stream>>>(emb, ws);
    fused_kernel<<<512, 256, 0, stream>>>(fea, W, b, ls, ws, out);
  } else {
    fallback_kernel<<<2048, 256, 0, stream>>>(fea, W, b, emb, ls, out);
  }
}